// Round 8
// baseline (237.778 us; speedup 1.0000x reference)
//
#include <hip/hip_runtime.h>

typedef _Float16 f16;
typedef _Float16 f16x8 __attribute__((ext_vector_type(8)));
typedef float f32x4 __attribute__((ext_vector_type(4)));

// async global->LDS, 16B per lane; LDS dest = wave-uniform base + lane*16
#define GLD16(g, l) __builtin_amdgcn_global_load_lds( \
    (const __attribute__((address_space(1))) void*)(g), \
    (__attribute__((address_space(3))) void*)(l), 16, 0, 0)

// ---------------------------------------------------------------------------
// Generic f16 MFMA GEMM, BK=64: C[m][n] = sum_k A[m][k]*B[n][k] (+bias)
// A: [M][K] f16 row-major, B: [N][K] f16 row-major (B^T layout).
// MODE: 0 none, 1 bias[col], 2 bias[row], 3 split-QK (col<768 -> C else C2).
// 256 threads = 4 waves (2x2); wave tile (BM/2)x(BN/2); MFMA 16x16x32_f16,
// two k-groups per K-step. Two-barrier single-buffer K-loop.
// LDS row = 64 f16 = 128 B; XOR swizzle: slot s of row r holds global chunk
// s^(r&7) -> ds_read_b128 bank-spread. Staging: one GLD16 issue = 8 rows.
//
// Session ledger (falsified levers -- do not retry):
//  R1 128x128@1.5blk/CU: -14us   R2 coarse counted-vmcnt dbuf: neutral
//  R4 fine ring BK=32: -30us     R5 96-wide tiles @2blk/CU: -9us
//  R6 XCD chunk-swizzle: -19us (PV FETCH 65->139MB; default round-robin
//     already L2-optimal for 2D grids)
//  R7 S-GEMM 128x128@4blk/CU: -5us (occupancy not the limiter either)
//  Flash fusion blocked: single-head D=768 -> O-tile needs 384 VGPR/lane.
// R8 lever (algebraic): out = P@(x@Wc^T + c) + bo with Wc=wo@wv, c=wo@bv
// (softmax rows sum to 1 -> bv passes through P as a constant). Deletes the
// 9.7 GF out-projection; PV writes fp32 d_out directly.
// ---------------------------------------------------------------------------
template <typename OutT, int BM, int BN, int MODE, int MINW>
__global__ __launch_bounds__(256, MINW)
void gemm_kernel(const f16* __restrict__ A, long sA,
                 const f16* __restrict__ B, long sB,
                 void* __restrict__ Cv, long sC,
                 void* __restrict__ C2v,
                 const float* __restrict__ bias,
                 const float* __restrict__ bias2,
                 int N, int K)
{
    constexpr int FM = BM / 32;
    constexpr int FN = BN / 32;
    constexpr int IA = BM / 32;
    constexpr int IB = BN / 32;

    OutT* C  = (OutT*)Cv;
    OutT* C2 = (OutT*)C2v;
    const int tid  = threadIdx.x;
    const int wave = tid >> 6;
    const int lane = tid & 63;
    const int bz   = blockIdx.z;
    A += (long)bz * sA;
    B += (long)bz * sB;
    C += (long)bz * sC;
    const long bm = (long)blockIdx.x * BM;
    const long bn = (long)blockIdx.y * BN;

    __shared__ f16 sAt[BM * 64];
    __shared__ f16 sBt[BN * 64];

    const int srow = lane >> 3;
    const int gch  = ((lane & 7) ^ srow) * 8;

    const f16* gAb = A + (bm + wave * (BM / 4) + srow) * (long)K + gch;
    const f16* gBb = B + (bn + wave * (BN / 4) + srow) * (long)K + gch;

    const int wm = (wave >> 1) * (BM / 2);
    const int wn = (wave & 1) * (BN / 2);
    const int lr = lane & 15;
    const int qd = lane >> 4;
    const int swz0 = ((0 * 4 + qd) ^ (lr & 7)) * 8;
    const int swz1 = ((1 * 4 + qd) ^ (lr & 7)) * 8;

    f32x4 acc[FM][FN] = {};

    for (int k0 = 0; k0 < K; k0 += 64) {
        #pragma unroll
        for (int i = 0; i < IA; ++i)
            GLD16(gAb + k0 + (long)i * 8 * K, &sAt[(wave * (BM / 4) + i * 8) * 64]);
        #pragma unroll
        for (int i = 0; i < IB; ++i)
            GLD16(gBb + k0 + (long)i * 8 * K, &sBt[(wave * (BN / 4) + i * 8) * 64]);
        __syncthreads();

        #pragma unroll
        for (int h = 0; h < 2; ++h) {
            const int swz = h ? swz1 : swz0;
            f16x8 af[FM], bf[FN];
            #pragma unroll
            for (int t = 0; t < FM; ++t)
                af[t] = *(const f16x8*)&sAt[(wm + t * 16 + lr) * 64 + swz];
            #pragma unroll
            for (int t = 0; t < FN; ++t)
                bf[t] = *(const f16x8*)&sBt[(wn + t * 16 + lr) * 64 + swz];
            #pragma unroll
            for (int tm = 0; tm < FM; ++tm)
                #pragma unroll
                for (int tn = 0; tn < FN; ++tn)
                    acc[tm][tn] = __builtin_amdgcn_mfma_f32_16x16x32_f16(
                        af[tm], bf[tn], acc[tm][tn], 0, 0, 0);
        }
        __syncthreads();
    }

    // epilogue: C/D layout col = lane&15, row = (lane>>4)*4 + reg
    #pragma unroll
    for (int tn = 0; tn < FN; ++tn) {
        const long col = bn + wn + tn * 16 + lr;
        OutT* dst = C;
        long cc = col, stride = N;
        float bc = 0.f;
        if (MODE == 1) bc = bias[col];
        if (MODE == 3) {
            stride = 768;
            if (col >= 768) { dst = C2; cc = col - 768; bc = bias2[cc]; }
            else            { bc = bias[cc]; }
        }
        #pragma unroll
        for (int tm = 0; tm < FM; ++tm) {
            #pragma unroll
            for (int r = 0; r < 4; ++r) {
                const long row = bm + wm + tm * 16 + qd * 4 + r;
                float v = acc[tm][tn][r] + bc;
                if (MODE == 2) v += bias[row];
                dst[row * stride + cc] = (OutT)v;
            }
        }
    }
}

// ---------------------------------------------------------------------------
// In-place row softmax over f16 scores; one block per row of 2048.
// fp32 math, unscaled (faithful to reference). HBM-bound (~11 us).
// ---------------------------------------------------------------------------
__global__ __launch_bounds__(256)
void softmax_kernel(f16* __restrict__ S)
{
    const long row = blockIdx.x;
    f16* p = S + row * 2048;
    const int tid  = threadIdx.x;
    const int wave = tid >> 6;
    const int lane = tid & 63;

    f16x8 x = *(const f16x8*)&p[tid * 8];
    float v[8];
    float m = -1e30f;
    #pragma unroll
    for (int j = 0; j < 8; ++j) { v[j] = (float)x[j]; m = fmaxf(m, v[j]); }
    #pragma unroll
    for (int off = 32; off > 0; off >>= 1) m = fmaxf(m, __shfl_down(m, off));

    __shared__ float rm[4], rs[4];
    if (lane == 0) rm[wave] = m;
    __syncthreads();
    m = fmaxf(fmaxf(rm[0], rm[1]), fmaxf(rm[2], rm[3]));

    float s = 0.f;
    #pragma unroll
    for (int j = 0; j < 8; ++j) { v[j] = __expf(v[j] - m); s += v[j]; }
    #pragma unroll
    for (int off = 32; off > 0; off >>= 1) s += __shfl_down(s, off);
    if (lane == 0) rs[wave] = s;
    __syncthreads();
    s = rs[0] + rs[1] + rs[2] + rs[3];
    const float inv = 1.0f / s;

    f16x8 y;
    #pragma unroll
    for (int j = 0; j < 8; ++j) y[j] = (f16)(v[j] * inv);
    *(f16x8*)&p[tid * 8] = y;
}

// ---------------------------------------------------------------------------
// fused fp32 -> f16 convert: blocks [0,3072) do x (6.29M elems),
// blocks [3072, 4224) do the 4 weight matrices (589824 elems each).
// ---------------------------------------------------------------------------
__global__ __launch_bounds__(256)
void cvt_all_kernel(const float* __restrict__ x,
                    const float* __restrict__ w0, const float* __restrict__ w1,
                    const float* __restrict__ w2, const float* __restrict__ w3,
                    f16* __restrict__ x16, f16* __restrict__ w16)
{
    const float* in; f16* out; long i;
    if (blockIdx.x < 3072) {
        in = x; out = x16;
        i = ((long)blockIdx.x * 256 + threadIdx.x) * 8;
    } else {
        const int wb  = blockIdx.x - 3072;
        const int sel = wb / 288;
        in  = (sel == 0) ? w0 : (sel == 1) ? w1 : (sel == 2) ? w2 : w3;
        out = w16 + (long)sel * 589824;
        i = ((long)(wb - sel * 288) * 256 + threadIdx.x) * 8;
    }
    float4 a = *(const float4*)(in + i);
    float4 b = *(const float4*)(in + i + 4);
    f16x8 o;
    o[0] = (f16)a.x; o[1] = (f16)a.y; o[2] = (f16)a.z; o[3] = (f16)a.w;
    o[4] = (f16)b.x; o[5] = (f16)b.y; o[6] = (f16)b.z; o[7] = (f16)b.w;
    *(f16x8*)&out[i] = o;
}

// ---------------------------------------------------------------------------
// 768x768 f16 transpose (wv16 -> wvT), 64x64 LDS tiles, grid (12,12).
// Needed to put wv into B^T layout for the Wc = wo@wv GEMM.
// ---------------------------------------------------------------------------
__global__ __launch_bounds__(256)
void transpose_kernel(const f16* __restrict__ in, f16* __restrict__ out)
{
    __shared__ f16 t[64][72];   // +8 pad: conflict-spread strided reads
    const int r  = threadIdx.x >> 2;
    const int c0 = (threadIdx.x & 3) * 16;
    const f16* src = in + ((long)blockIdx.x * 64 + r) * 768 + blockIdx.y * 64 + c0;
    f16x8 a = *(const f16x8*)src;
    f16x8 b = *(const f16x8*)(src + 8);
    #pragma unroll
    for (int i = 0; i < 8; ++i) { t[r][c0 + i] = a[i]; t[r][c0 + 8 + i] = b[i]; }
    __syncthreads();
    f16x8 o1, o2;
    #pragma unroll
    for (int i = 0; i < 8; ++i) { o1[i] = t[c0 + i][r]; o2[i] = t[c0 + 8 + i][r]; }
    f16* dst = out + ((long)blockIdx.y * 64 + r) * 768 + blockIdx.x * 64 + c0;
    *(f16x8*)dst = o1;
    *(f16x8*)(dst + 8) = o2;
}

// ---------------------------------------------------------------------------
// c[d] = sum_h wo[d][h] * bv[h]  (fp32, one block per output d).
// ---------------------------------------------------------------------------
__global__ __launch_bounds__(256)
void wobv_kernel(const float* __restrict__ wo, const float* __restrict__ bv,
                 float* __restrict__ c)
{
    const int d = blockIdx.x;
    const int tid = threadIdx.x;
    float s = 0.f;
    for (int h = tid; h < 768; h += 256) s += wo[d * 768 + h] * bv[h];
    #pragma unroll
    for (int off = 32; off > 0; off >>= 1) s += __shfl_down(s, off);
    __shared__ float rs[4];
    if ((tid & 63) == 0) rs[tid >> 6] = s;
    __syncthreads();
    if (tid == 0) c[d] = rs[0] + rs[1] + rs[2] + rs[3];
}

// ---------------------------------------------------------------------------
// B=4, S=2048, D=H=768.  ws layout (bytes):
//   x16 @0 (12.6MB) | w16 @12582912 (4.7MB: wq,wk,wv,wo) | Q @17301504
//   K @29884416 | VWT @42467328 ([4][768][2048]) | S @55050240 (33.5MB)
//   wvT @88604672 (1.18MB) | Wc @89784320 (1.18MB) | c @90963968 (3KB)
//   total ~91 MB
// ---------------------------------------------------------------------------
extern "C" void kernel_launch(void* const* d_in, const int* in_sizes, int n_in,
                              void* d_out, int out_size, void* d_ws, size_t ws_size,
                              hipStream_t stream)
{
    const float* x  = (const float*)d_in[0];
    const float* wq = (const float*)d_in[1];
    const float* bq = (const float*)d_in[2];
    const float* wk = (const float*)d_in[3];
    const float* bk = (const float*)d_in[4];
    const float* wv = (const float*)d_in[5];
    const float* bv = (const float*)d_in[6];
    const float* wo = (const float*)d_in[7];
    const float* bo = (const float*)d_in[8];

    char* ws = (char*)d_ws;
    f16* x16  = (f16*)(ws + 0);
    f16* w16  = (f16*)(ws + 12582912);
    f16* Q    = (f16*)(ws + 17301504);
    f16* Kb   = (f16*)(ws + 29884416);
    f16* VWT  = (f16*)(ws + 42467328);
    f16* S    = (f16*)(ws + 55050240);
    f16* wvT  = (f16*)(ws + 88604672);
    f16* Wc   = (f16*)(ws + 89784320);
    float* cB = (float*)(ws + 90963968);

    f16* wv16 = w16 + 2 * 589824;
    f16* wo16 = w16 + 3 * 589824;

    cvt_all_kernel<<<4224, 256, 0, stream>>>(x, wq, wk, wv, wo, x16, w16);

    // wvT[k][h] = wv[h][k] (f16, 1.2MB)
    transpose_kernel<<<dim3(12, 12), 256, 0, stream>>>(wv16, wvT);
    // c = wo @ bv (fp32)
    wobv_kernel<<<768, 256, 0, stream>>>(wo, bv, cB);
    // Wc[d][k] = sum_h wo[d][h] wv[h][k] : A=wo16, B=wvT, 0.9 GF, 36 blocks
    gemm_kernel<f16, 128, 128, 0, 3><<<dim3(6, 6, 1), 256, 0, stream>>>(
        wo16, 0, wvT, 0, Wc, 0, nullptr, nullptr, nullptr, 768, 768);

    // fused Q|K projection: B = [wq;wk], N=1536, 768 blocks = 3/CU (R0).
    gemm_kernel<f16, 128, 128, 3, 3><<<dim3(64, 12, 1), 256, 0, stream>>>(
        x16, 0, w16, 0, Q, 0, Kb, bq, bk, 1536, 768);
    // VWT[b][d][s] = sum_k Wc[d][k] x[b][s][k] + c[d]  (row-bias, R0 V-proj
    // shape: 64x128, 768 blocks = 3/CU)
    gemm_kernel<f16, 64, 128, 2, 4><<<dim3(12, 16, 4), 256, 0, stream>>>(
        Wc, 0, x16, (long)2048 * 768, VWT, (long)768 * 2048, nullptr,
        cB, nullptr, 2048, 768);
    // S[b] = Q[b] @ K[b]^T : 128x256, 512 blocks = 2/CU (R0-proven).
    gemm_kernel<f16, 128, 256, 0, 2><<<dim3(16, 8, 4), 256, 0, stream>>>(
        Q, (long)2048 * 768, Kb, (long)2048 * 768, S, (long)2048 * 2048,
        nullptr, nullptr, nullptr, 2048, 768);
    softmax_kernel<<<8192, 256, 0, stream>>>(S);
    // out[b][q][d] = sum_k P[q][k] VWT[d][k] + bo[d] : fp32 out, col-bias,
    // 128x64, 768 blocks = 3/CU, K=2048. (Old PV + out-proj collapsed.)
    gemm_kernel<float, 128, 64, 1, 4><<<dim3(16, 12, 4), 256, 0, stream>>>(
        S, (long)2048 * 2048, VWT, (long)768 * 2048, d_out, (long)2048 * 768,
        nullptr, bo, nullptr, 768, 2048);
}

// Round 10
// 228.029 us; speedup vs baseline: 1.0428x; 1.0428x over previous
//
#include <hip/hip_runtime.h>

typedef _Float16 f16;
typedef _Float16 f16x8 __attribute__((ext_vector_type(8)));
typedef float f32x4 __attribute__((ext_vector_type(4)));

// async global->LDS, 16B per lane; LDS dest = wave-uniform base + lane*16
#define GLD16(g, l) __builtin_amdgcn_global_load_lds( \
    (const __attribute__((address_space(1))) void*)(g), \
    (__attribute__((address_space(3))) void*)(l), 16, 0, 0)

// ---------------------------------------------------------------------------
// Generic f16 MFMA GEMM, BK=64: C[m][n] = sum_k A[m][k]*B[n][k] (+bias)
// A: [M][K] f16 row-major, B: [N][K] f16 row-major (B^T layout).
// MODE: 0 none, 1 bias[col], 2 bias[row], 3 split-QK (col<768 -> C else C2)
//   + (MODE 3 only) last grid-y row multiplexes a secondary 768x768x768 GEMM
//     C3 = A2 @ B2^T (36 blocks; rest exit) -- saves one dispatch.
// 256 threads = 4 waves (2x2); wave tile (BM/2)x(BN/2); MFMA 16x16x32_f16.
// Two-barrier single-buffer K-loop. LDS row = 64 f16 = 128 B; XOR swizzle:
// slot s of row r holds global chunk s^(r&7) -> conflict-free ds_read_b128.
//
// Session ledger (falsified levers -- do not retry):
//  R1 128x128@1.5blk/CU: -14us   R2 coarse counted-vmcnt dbuf: neutral
//  R4 fine ring BK=32: -30us     R5 96-wide tiles @2blk/CU: -9us
//  R6 XCD chunk-swizzle: -19us (default round-robin already L2-optimal)
//  R7 S-GEMM @4blk/CU: -5us (occupancy not the limiter)
//  R8 algebraic out-proj removal: work -19GF but +2 dispatches, total +2us
//    -> per-dispatch overhead ~5-10us dominates; R9 fuses 9->6 dispatches.
// ---------------------------------------------------------------------------
template <typename OutT, int BM, int BN, int MODE, int MINW>
__global__ __launch_bounds__(256, MINW)
void gemm_kernel(const f16* __restrict__ A, long sA,
                 const f16* __restrict__ B, long sB,
                 void* __restrict__ Cv, long sC,
                 void* __restrict__ C2v,
                 const float* __restrict__ bias,
                 const float* __restrict__ bias2,
                 int N, int K,
                 const f16* __restrict__ A2,
                 const f16* __restrict__ B2,
                 void* __restrict__ C3v)
{
    constexpr int FM = BM / 32;
    constexpr int FN = BN / 32;
    constexpr int IA = BM / 32;
    constexpr int IB = BN / 32;

    OutT* C  = (OutT*)Cv;
    OutT* C2 = (OutT*)C2v;
    const int tid  = threadIdx.x;
    const int wave = tid >> 6;
    const int lane = tid & 63;
    const int bz   = blockIdx.z;

    const f16* Ab = A + (long)bz * sA;
    const f16* Bb = B + (long)bz * sB;
    C += (long)bz * sC;
    int Kk = K;
    long bm, bn;
    bool sub = false;
    if (MODE == 3 && blockIdx.y == gridDim.y - 1) {
        if (blockIdx.x >= 36) return;          // 36 tiles cover 768x768
        sub = true;
        Ab = A2; Bb = B2; Kk = 768;
        bm = (long)(blockIdx.x / 6) * BM;
        bn = (long)(blockIdx.x % 6) * BN;
    } else {
        bm = (long)blockIdx.x * BM;
        bn = (long)blockIdx.y * BN;
    }

    __shared__ f16 sAt[BM * 64];
    __shared__ f16 sBt[BN * 64];

    const int srow = lane >> 3;
    const int gch  = ((lane & 7) ^ srow) * 8;

    const f16* gAb = Ab + (bm + wave * (BM / 4) + srow) * (long)Kk + gch;
    const f16* gBb = Bb + (bn + wave * (BN / 4) + srow) * (long)Kk + gch;

    const int wm = (wave >> 1) * (BM / 2);
    const int wn = (wave & 1) * (BN / 2);
    const int lr = lane & 15;
    const int qd = lane >> 4;
    const int swz0 = ((0 * 4 + qd) ^ (lr & 7)) * 8;
    const int swz1 = ((1 * 4 + qd) ^ (lr & 7)) * 8;

    f32x4 acc[FM][FN] = {};

    for (int k0 = 0; k0 < Kk; k0 += 64) {
        #pragma unroll
        for (int i = 0; i < IA; ++i)
            GLD16(gAb + k0 + (long)i * 8 * Kk, &sAt[(wave * (BM / 4) + i * 8) * 64]);
        #pragma unroll
        for (int i = 0; i < IB; ++i)
            GLD16(gBb + k0 + (long)i * 8 * Kk, &sBt[(wave * (BN / 4) + i * 8) * 64]);
        __syncthreads();

        #pragma unroll
        for (int h = 0; h < 2; ++h) {
            const int swz = h ? swz1 : swz0;
            f16x8 af[FM], bf[FN];
            #pragma unroll
            for (int t = 0; t < FM; ++t)
                af[t] = *(const f16x8*)&sAt[(wm + t * 16 + lr) * 64 + swz];
            #pragma unroll
            for (int t = 0; t < FN; ++t)
                bf[t] = *(const f16x8*)&sBt[(wn + t * 16 + lr) * 64 + swz];
            #pragma unroll
            for (int tm = 0; tm < FM; ++tm)
                #pragma unroll
                for (int tn = 0; tn < FN; ++tn)
                    acc[tm][tn] = __builtin_amdgcn_mfma_f32_16x16x32_f16(
                        af[tm], bf[tn], acc[tm][tn], 0, 0, 0);
        }
        __syncthreads();
    }

    // epilogue: C/D layout col = lane&15, row = (lane>>4)*4 + reg
    if (MODE == 3 && sub) {
        f16* W = (f16*)C3v;
        #pragma unroll
        for (int tn = 0; tn < FN; ++tn) {
            const long col = bn + wn + tn * 16 + lr;
            #pragma unroll
            for (int tm = 0; tm < FM; ++tm)
                #pragma unroll
                for (int r = 0; r < 4; ++r) {
                    const long row = bm + wm + tm * 16 + qd * 4 + r;
                    W[row * 768 + col] = (f16)acc[tm][tn][r];
                }
        }
        return;
    }
    #pragma unroll
    for (int tn = 0; tn < FN; ++tn) {
        const long col = bn + wn + tn * 16 + lr;
        OutT* dst = C;
        long cc = col, stride = N;
        float bc = 0.f;
        if (MODE == 1) bc = bias[col];
        if (MODE == 3) {
            stride = 768;
            if (col >= 768) { dst = C2; cc = col - 768; bc = bias2[cc]; }
            else            { bc = bias[cc]; }
        }
        #pragma unroll
        for (int tm = 0; tm < FM; ++tm) {
            #pragma unroll
            for (int r = 0; r < 4; ++r) {
                const long row = bm + wm + tm * 16 + qd * 4 + r;
                float v = acc[tm][tn][r] + bc;
                if (MODE == 2) v += bias[row];
                dst[row * stride + cc] = (OutT)v;
            }
        }
    }
}

// ---------------------------------------------------------------------------
// In-place row softmax over f16 scores; one block per row of 2048.
// fp32 math, unscaled. HBM-bound (~11 us at 6.1 TB/s eff).
// ---------------------------------------------------------------------------
__global__ __launch_bounds__(256)
void softmax_kernel(f16* __restrict__ S)
{
    const long row = blockIdx.x;
    f16* p = S + row * 2048;
    const int tid  = threadIdx.x;
    const int wave = tid >> 6;
    const int lane = tid & 63;

    f16x8 x = *(const f16x8*)&p[tid * 8];
    float v[8];
    float m = -1e30f;
    #pragma unroll
    for (int j = 0; j < 8; ++j) { v[j] = (float)x[j]; m = fmaxf(m, v[j]); }
    #pragma unroll
    for (int off = 32; off > 0; off >>= 1) m = fmaxf(m, __shfl_down(m, off));

    __shared__ float rm[4], rs[4];
    if (lane == 0) rm[wave] = m;
    __syncthreads();
    m = fmaxf(fmaxf(rm[0], rm[1]), fmaxf(rm[2], rm[3]));

    float s = 0.f;
    #pragma unroll
    for (int j = 0; j < 8; ++j) { v[j] = __expf(v[j] - m); s += v[j]; }
    #pragma unroll
    for (int off = 32; off > 0; off >>= 1) s += __shfl_down(s, off);
    if (lane == 0) rs[wave] = s;
    __syncthreads();
    s = rs[0] + rs[1] + rs[2] + rs[3];
    const float inv = 1.0f / s;

    f16x8 y;
    #pragma unroll
    for (int j = 0; j < 8; ++j) y[j] = (f16)(v[j] * inv);
    *(f16x8*)&p[tid * 8] = y;
}

// ---------------------------------------------------------------------------
// Fused prep (ONE dispatch):
//  [0,3072):      x fp32 -> x16          (2048 elems/block)
//  [3072,3360):   wq -> w16+0
//  [3360,3648):   wk -> w16+589824
//  [3648,3936):   wo -> w16+3*589824
//  [3936,4080):   wv tiled 64x64 -> wv16 (w16+2*589824) AND wvT (transpose)
//  [4080,4092):   c = wo @ bv  (12 blocks x 64 rows, one wave per row)
// ---------------------------------------------------------------------------
__global__ __launch_bounds__(256)
void cvt_all_kernel(const float* __restrict__ x,
                    const float* __restrict__ wq, const float* __restrict__ wk,
                    const float* __restrict__ wv, const float* __restrict__ wo,
                    const float* __restrict__ bv,
                    f16* __restrict__ x16, f16* __restrict__ w16,
                    f16* __restrict__ wvT, float* __restrict__ cB)
{
    __shared__ f16 t[64][72];
    const int b = blockIdx.x;
    const int tid = threadIdx.x;

    if (b < 3936) {
        const float* in; f16* out; long i;
        if (b < 3072) {
            in = x; out = x16;
            i = ((long)b * 256 + tid) * 8;
        } else {
            const int wb  = b - 3072;
            const int sel = wb / 288;            // 0=wq 1=wk 2=wo
            in  = (sel == 0) ? wq : (sel == 1) ? wk : wo;
            out = w16 + (long)((sel == 2) ? 3 : sel) * 589824;
            i = ((long)(wb - sel * 288) * 256 + tid) * 8;
        }
        float4 a = *(const float4*)(in + i);
        float4 c = *(const float4*)(in + i + 4);
        f16x8 o;
        o[0] = (f16)a.x; o[1] = (f16)a.y; o[2] = (f16)a.z; o[3] = (f16)a.w;
        o[4] = (f16)c.x; o[5] = (f16)c.y; o[6] = (f16)c.z; o[7] = (f16)c.w;
        *(f16x8*)&out[i] = o;
    } else if (b < 4080) {
        // wv tiled cvt + transpose: tile (tr,tc), 64x64
        const int tb = b - 3936;
        const int tr = tb / 12, tc = tb % 12;
        const int r  = tid >> 2;
        const int c0 = (tid & 3) * 16;
        const float* src = wv + ((long)tr * 64 + r) * 768 + tc * 64 + c0;
        float4 a0 = *(const float4*)(src);
        float4 a1 = *(const float4*)(src + 4);
        float4 a2 = *(const float4*)(src + 8);
        float4 a3 = *(const float4*)(src + 12);
        f16 vv[16];
        vv[0]=(f16)a0.x; vv[1]=(f16)a0.y; vv[2]=(f16)a0.z; vv[3]=(f16)a0.w;
        vv[4]=(f16)a1.x; vv[5]=(f16)a1.y; vv[6]=(f16)a1.z; vv[7]=(f16)a1.w;
        vv[8]=(f16)a2.x; vv[9]=(f16)a2.y; vv[10]=(f16)a2.z; vv[11]=(f16)a2.w;
        vv[12]=(f16)a3.x; vv[13]=(f16)a3.y; vv[14]=(f16)a3.z; vv[15]=(f16)a3.w;
        f16* wv16 = w16 + (long)2 * 589824;
        f16x8 o1, o2;
        #pragma unroll
        for (int i = 0; i < 8; ++i) { o1[i] = vv[i]; o2[i] = vv[8 + i]; }
        f16* d16 = wv16 + ((long)tr * 64 + r) * 768 + tc * 64 + c0;
        *(f16x8*)d16 = o1;
        *(f16x8*)(d16 + 8) = o2;
        #pragma unroll
        for (int i = 0; i < 16; ++i) t[r][c0 + i] = vv[i];
        __syncthreads();
        #pragma unroll
        for (int i = 0; i < 8; ++i) { o1[i] = t[c0 + i][r]; o2[i] = t[c0 + 8 + i][r]; }
        f16* dT = wvT + ((long)tc * 64 + r) * 768 + tr * 64 + c0;
        *(f16x8*)dT = o1;
        *(f16x8*)(dT + 8) = o2;
    } else {
        // c[d] = sum_h wo[d][h]*bv[h]; one wave per d, 16 iterations
        const int d0 = (b - 4080) * 64;
        const int wave = tid >> 6, lane = tid & 63;
        for (int it = 0; it < 16; ++it) {
            const int d = d0 + it * 4 + wave;
            float s = 0.f;
            #pragma unroll
            for (int j = 0; j < 12; ++j) {
                const int h = lane + 64 * j;
                s += wo[(long)d * 768 + h] * bv[h];
            }
            #pragma unroll
            for (int off = 32; off > 0; off >>= 1) s += __shfl_down(s, off);
            if (lane == 0) cB[d] = s;
        }
    }
}

// ---------------------------------------------------------------------------
// B=4, S=2048, D=H=768.  out = P @ (x@Wc^T + c) + bo, Wc = wo@wv, c = wo@bv
// (softmax rows sum to 1 -> bv passes through P as a constant).
// ws layout (bytes):
//   x16 @0 (12.6MB) | w16 @12582912 (4.7MB) | Q @17301504 | K @29884416
//   VWT @42467328 ([4][768][2048]) | S @55050240 (33.5MB)
//   wvT @88604672 | Wc @89784320 | c @90963968    total ~91 MB
// 6 dispatches: cvt+T+wobv | QK+Wc | VWT | S | softmax | PVout
// ---------------------------------------------------------------------------
extern "C" void kernel_launch(void* const* d_in, const int* in_sizes, int n_in,
                              void* d_out, int out_size, void* d_ws, size_t ws_size,
                              hipStream_t stream)
{
    const float* x  = (const float*)d_in[0];
    const float* wq = (const float*)d_in[1];
    const float* bq = (const float*)d_in[2];
    const float* wk = (const float*)d_in[3];
    const float* bk = (const float*)d_in[4];
    const float* wv = (const float*)d_in[5];
    const float* bv = (const float*)d_in[6];
    const float* wo = (const float*)d_in[7];
    const float* bo = (const float*)d_in[8];

    char* ws = (char*)d_ws;
    f16* x16  = (f16*)(ws + 0);
    f16* w16  = (f16*)(ws + 12582912);
    f16* Q    = (f16*)(ws + 17301504);
    f16* Kb   = (f16*)(ws + 29884416);
    f16* VWT  = (f16*)(ws + 42467328);
    f16* S    = (f16*)(ws + 55050240);
    f16* wvT  = (f16*)(ws + 88604672);
    f16* Wc   = (f16*)(ws + 89784320);
    float* cB = (float*)(ws + 90963968);

    f16* wo16 = w16 + 3 * 589824;

    // 1) all conversions + wv transpose + c = wo@bv
    cvt_all_kernel<<<4092, 256, 0, stream>>>(x, wq, wk, wv, wo, bv,
                                             x16, w16, wvT, cB);
    // 2) fused Q|K projection (768 blocks, rows 0-11) + Wc = wo@wv (row 12)
    gemm_kernel<f16, 128, 128, 3, 3><<<dim3(64, 13, 1), 256, 0, stream>>>(
        x16, 0, w16, 0, Q, 0, Kb, bq, bk, 1536, 768, wo16, wvT, Wc);
    // 3) VWT[b][d][s] = sum_k Wc[d][k] x[b][s][k] + c[d]  (row-bias, 64x128,
    //    768 blocks = 3/CU)
    gemm_kernel<f16, 64, 128, 2, 4><<<dim3(12, 16, 4), 256, 0, stream>>>(
        Wc, 0, x16, (long)2048 * 768, VWT, (long)768 * 2048, nullptr,
        cB, nullptr, 2048, 768, nullptr, nullptr, nullptr);
    // 4) S[b] = Q[b] @ K[b]^T : 128x256, 512 blocks = 2/CU (R0-proven).
    gemm_kernel<f16, 128, 256, 0, 2><<<dim3(16, 8, 4), 256, 0, stream>>>(
        Q, (long)2048 * 768, Kb, (long)2048 * 768, S, (long)2048 * 2048,
        nullptr, nullptr, nullptr, 2048, 768, nullptr, nullptr, nullptr);
    // 5) softmax
    softmax_kernel<<<8192, 256, 0, stream>>>(S);
    // 6) out[b][q][d] = sum_k P[q][k] VWT[d][k] + bo[d] : fp32 out, col-bias,
    //    128x64, 768 blocks = 3/CU, K=2048 (old PV + out-proj collapsed).
    gemm_kernel<float, 128, 64, 1, 4><<<dim3(16, 12, 4), 256, 0, stream>>>(
        S, (long)2048 * 2048, VWT, (long)768 * 2048, d_out, (long)2048 * 768,
        nullptr, bo, nullptr, 768, 2048, nullptr, nullptr, nullptr);
}

// Round 11
// 227.783 us; speedup vs baseline: 1.0439x; 1.0011x over previous
//
#include <hip/hip_runtime.h>

typedef _Float16 f16;
typedef _Float16 f16x8 __attribute__((ext_vector_type(8)));
typedef float f32x4 __attribute__((ext_vector_type(4)));

// async global->LDS, 16B per lane; LDS dest = wave-uniform base + lane*16
#define GLD16(g, l) __builtin_amdgcn_global_load_lds( \
    (const __attribute__((address_space(1))) void*)(g), \
    (__attribute__((address_space(3))) void*)(l), 16, 0, 0)

// ---------------------------------------------------------------------------
// Generic f16 MFMA GEMM, BK=64: C[m][n] = sum_k A[m][k]*B[n][k] (+bias)
// A: [M][K] f16 row-major, B: [N][K] f16 row-major (B^T layout).
// MODE 0 none / 1 bias[col] (plain z-grid modes), plus POOLED modes:
//  MODE 4 (flat 804, 128x128): idx<768 QK-proj (split Q|K epilogue, bq/bk);
//          idx>=768: 36-block Wc = wo @ wvT (plain f16, stride 768).
//  MODE 5 (flat 704, 128x256): idx<512 S = Q@K^T per batch (plain, 2048);
//          idx>=512: 192-block VWT[b][d][s] = sum_k Wc[d][k] x[b][s][k]
//          + cB[d] (row-bias, stride 2048). Pools a 2/CU-starved S with
//          VWT's blocks -> ~2.75 blocks/CU homogeneous pool.
// 256 threads = 4 waves (2x2); wave tile (BM/2)x(BN/2); MFMA 16x16x32_f16.
// Two-barrier single-buffer K-loop. LDS row = 64 f16 = 128 B; XOR swizzle:
// slot s of row r holds global chunk s^(r&7) -> conflict-free ds_read_b128.
//
// Session ledger (falsified levers -- do not retry):
//  R1 128x128@1.5blk/CU: -14us   R2 coarse counted-vmcnt dbuf: neutral
//  R4 fine ring BK=32: -30us     R5 96-wide tiles @2blk/CU: -9us
//  R6 XCD chunk-swizzle: -19us   R7 S-GEMM @4blk/CU: -5us
//  R8 algebra alone: +8us (work is not the limiter)
//  R10 dispatch fusion 9->6: -10us  => overhead ~3us/dispatch + fixed
//  ~75us (harness fills + graph gaps). R11: pool 6->5, pack VWT into S.
// ---------------------------------------------------------------------------
template <typename OutT, int BM, int BN, int MODE, int MINW>
__global__ __launch_bounds__(256, MINW)
void gemm_kernel(const f16* __restrict__ A, long sA,
                 const f16* __restrict__ B, long sB,
                 void* __restrict__ Cv, long sC,
                 void* __restrict__ C2v,
                 const float* __restrict__ bias,
                 const float* __restrict__ bias2,
                 int N, int K,
                 const f16* __restrict__ A2,
                 const f16* __restrict__ B2,
                 void* __restrict__ C3v,
                 const float* __restrict__ bias3)
{
    constexpr int FM = BM / 32;
    constexpr int FN = BN / 32;
    constexpr int IA = BM / 32;
    constexpr int IB = BN / 32;

    const int tid  = threadIdx.x;
    const int wave = tid >> 6;
    const int lane = tid & 63;

    const f16* Ab;
    const f16* Bb;
    long bm, bn;
    long czoff = 0;
    int  job = 0;

    if (MODE == 4) {
        const int idx = blockIdx.x;
        if (idx < 768) {                       // QK-proj: M=8192, N=1536
            Ab = A; Bb = B;
            bm = (long)(idx & 63) * BM;
            bn = (long)(idx >> 6) * BN;
        } else {                               // Wc = wo @ wvT (768^3)
            job = 1;
            const int t = idx - 768;           // 0..35
            Ab = A2; Bb = B2;
            bm = (long)(t / 6) * BM;
            bn = (long)(t % 6) * BN;
        }
    } else if (MODE == 5) {
        const int idx = blockIdx.x;
        if (idx < 512) {                       // S[b] = Q@K^T, 16x8 tiles/b
            const int sz = idx >> 7, r = idx & 127;
            Ab = A + (long)sz * 1572864;
            Bb = B + (long)sz * 1572864;
            bm = (long)(r & 15) * BM;
            bn = (long)(r >> 4) * BN;
            czoff = (long)sz * 4194304;
        } else {                               // VWT[b] = Wc@x^T, 6x8/b
            job = 1;
            const int t = idx - 512;           // 0..191
            const int vz = t / 48, r = t % 48;
            Ab = A2;
            Bb = B2 + (long)vz * 1572864;
            bm = (long)(r % 6) * BM;
            bn = (long)(r / 6) * BN;
            czoff = (long)vz * 1572864;
        }
    } else {
        Ab = A + (long)blockIdx.z * sA;
        Bb = B + (long)blockIdx.z * sB;
        bm = (long)blockIdx.x * BM;
        bn = (long)blockIdx.y * BN;
        czoff = (long)blockIdx.z * sC;
    }

    __shared__ f16 sAt[BM * 64];
    __shared__ f16 sBt[BN * 64];

    const int srow = lane >> 3;
    const int gch  = ((lane & 7) ^ srow) * 8;

    const f16* gAb = Ab + (bm + wave * (BM / 4) + srow) * (long)K + gch;
    const f16* gBb = Bb + (bn + wave * (BN / 4) + srow) * (long)K + gch;

    const int wm = (wave >> 1) * (BM / 2);
    const int wn = (wave & 1) * (BN / 2);
    const int lr = lane & 15;
    const int qd = lane >> 4;
    const int swz0 = ((0 * 4 + qd) ^ (lr & 7)) * 8;
    const int swz1 = ((1 * 4 + qd) ^ (lr & 7)) * 8;

    f32x4 acc[FM][FN] = {};

    for (int k0 = 0; k0 < K; k0 += 64) {
        #pragma unroll
        for (int i = 0; i < IA; ++i)
            GLD16(gAb + k0 + (long)i * 8 * K, &sAt[(wave * (BM / 4) + i * 8) * 64]);
        #pragma unroll
        for (int i = 0; i < IB; ++i)
            GLD16(gBb + k0 + (long)i * 8 * K, &sBt[(wave * (BN / 4) + i * 8) * 64]);
        __syncthreads();

        #pragma unroll
        for (int h = 0; h < 2; ++h) {
            const int swz = h ? swz1 : swz0;
            f16x8 af[FM], bf[FN];
            #pragma unroll
            for (int t = 0; t < FM; ++t)
                af[t] = *(const f16x8*)&sAt[(wm + t * 16 + lr) * 64 + swz];
            #pragma unroll
            for (int t = 0; t < FN; ++t)
                bf[t] = *(const f16x8*)&sBt[(wn + t * 16 + lr) * 64 + swz];
            #pragma unroll
            for (int tm = 0; tm < FM; ++tm)
                #pragma unroll
                for (int tn = 0; tn < FN; ++tn)
                    acc[tm][tn] = __builtin_amdgcn_mfma_f32_16x16x32_f16(
                        af[tm], bf[tn], acc[tm][tn], 0, 0, 0);
        }
        __syncthreads();
    }

    // epilogue: C/D layout col = lane&15, row = (lane>>4)*4 + reg
    if (MODE == 4) {
        if (job == 1) {                        // Wc tile: plain f16, ld 768
            f16* W = (f16*)C3v;
            #pragma unroll
            for (int tn = 0; tn < FN; ++tn) {
                const long col = bn + wn + tn * 16 + lr;
                #pragma unroll
                for (int tm = 0; tm < FM; ++tm)
                    #pragma unroll
                    for (int r = 0; r < 4; ++r) {
                        const long row = bm + wm + tm * 16 + qd * 4 + r;
                        W[row * 768 + col] = (f16)acc[tm][tn][r];
                    }
            }
            return;
        }
        // QK split: col<768 -> C (Q, +bq), else C2 (K, +bk); ld 768 each
        f16* Qd = (f16*)Cv;
        f16* Kd = (f16*)C2v;
        #pragma unroll
        for (int tn = 0; tn < FN; ++tn) {
            const long col = bn + wn + tn * 16 + lr;
            f16* dst = Qd;
            long cc = col;
            float bc;
            if (col >= 768) { dst = Kd; cc = col - 768; bc = bias2[cc]; }
            else            { bc = bias[cc]; }
            #pragma unroll
            for (int tm = 0; tm < FM; ++tm)
                #pragma unroll
                for (int r = 0; r < 4; ++r) {
                    const long row = bm + wm + tm * 16 + qd * 4 + r;
                    dst[row * 768 + cc] = (f16)(acc[tm][tn][r] + bc);
                }
        }
        return;
    }
    if (MODE == 5) {
        if (job == 1) {                        // VWT: row-bias cB[d], ld 2048
            f16* W = (f16*)C3v + czoff;
            #pragma unroll
            for (int tn = 0; tn < FN; ++tn) {
                const long col = bn + wn + tn * 16 + lr;
                #pragma unroll
                for (int tm = 0; tm < FM; ++tm)
                    #pragma unroll
                    for (int r = 0; r < 4; ++r) {
                        const long row = bm + wm + tm * 16 + qd * 4 + r;
                        W[row * 2048 + col] = (f16)(acc[tm][tn][r] + bias3[row]);
                    }
            }
            return;
        }
        f16* W = (f16*)Cv + czoff;             // S: plain f16, ld 2048
        #pragma unroll
        for (int tn = 0; tn < FN; ++tn) {
            const long col = bn + wn + tn * 16 + lr;
            #pragma unroll
            for (int tm = 0; tm < FM; ++tm)
                #pragma unroll
                for (int r = 0; r < 4; ++r) {
                    const long row = bm + wm + tm * 16 + qd * 4 + r;
                    W[row * 2048 + col] = (f16)acc[tm][tn][r];
                }
        }
        return;
    }
    // plain modes 0/1
    OutT* C = (OutT*)Cv + czoff;
    #pragma unroll
    for (int tn = 0; tn < FN; ++tn) {
        const long col = bn + wn + tn * 16 + lr;
        float bc = (MODE == 1) ? bias[col] : 0.f;
        #pragma unroll
        for (int tm = 0; tm < FM; ++tm) {
            #pragma unroll
            for (int r = 0; r < 4; ++r) {
                const long row = bm + wm + tm * 16 + qd * 4 + r;
                C[row * (long)N + col] = (OutT)(acc[tm][tn][r] + bc);
            }
        }
    }
}

// ---------------------------------------------------------------------------
// In-place row softmax over f16 scores; one block per row of 2048.
// fp32 math, unscaled. HBM-bound (~11 us at 6.1 TB/s eff).
// ---------------------------------------------------------------------------
__global__ __launch_bounds__(256)
void softmax_kernel(f16* __restrict__ S)
{
    const long row = blockIdx.x;
    f16* p = S + row * 2048;
    const int tid  = threadIdx.x;
    const int wave = tid >> 6;
    const int lane = tid & 63;

    f16x8 x = *(const f16x8*)&p[tid * 8];
    float v[8];
    float m = -1e30f;
    #pragma unroll
    for (int j = 0; j < 8; ++j) { v[j] = (float)x[j]; m = fmaxf(m, v[j]); }
    #pragma unroll
    for (int off = 32; off > 0; off >>= 1) m = fmaxf(m, __shfl_down(m, off));

    __shared__ float rm[4], rs[4];
    if (lane == 0) rm[wave] = m;
    __syncthreads();
    m = fmaxf(fmaxf(rm[0], rm[1]), fmaxf(rm[2], rm[3]));

    float s = 0.f;
    #pragma unroll
    for (int j = 0; j < 8; ++j) { v[j] = __expf(v[j] - m); s += v[j]; }
    #pragma unroll
    for (int off = 32; off > 0; off >>= 1) s += __shfl_down(s, off);
    if (lane == 0) rs[wave] = s;
    __syncthreads();
    s = rs[0] + rs[1] + rs[2] + rs[3];
    const float inv = 1.0f / s;

    f16x8 y;
    #pragma unroll
    for (int j = 0; j < 8; ++j) y[j] = (f16)(v[j] * inv);
    *(f16x8*)&p[tid * 8] = y;
}

// ---------------------------------------------------------------------------
// Fused prep (ONE dispatch):
//  [0,3072):      x fp32 -> x16          (2048 elems/block)
//  [3072,3360):   wq -> w16+0
//  [3360,3648):   wk -> w16+589824
//  [3648,3936):   wo -> w16+3*589824
//  [3936,4080):   wv tiled 64x64 -> wv16 (w16+2*589824) AND wvT (transpose)
//  [4080,4092):   c = wo @ bv  (12 blocks x 64 rows, one wave per row)
// ---------------------------------------------------------------------------
__global__ __launch_bounds__(256)
void cvt_all_kernel(const float* __restrict__ x,
                    const float* __restrict__ wq, const float* __restrict__ wk,
                    const float* __restrict__ wv, const float* __restrict__ wo,
                    const float* __restrict__ bv,
                    f16* __restrict__ x16, f16* __restrict__ w16,
                    f16* __restrict__ wvT, float* __restrict__ cB)
{
    __shared__ f16 t[64][72];
    const int b = blockIdx.x;
    const int tid = threadIdx.x;

    if (b < 3936) {
        const float* in; f16* out; long i;
        if (b < 3072) {
            in = x; out = x16;
            i = ((long)b * 256 + tid) * 8;
        } else {
            const int wb  = b - 3072;
            const int sel = wb / 288;            // 0=wq 1=wk 2=wo
            in  = (sel == 0) ? wq : (sel == 1) ? wk : wo;
            out = w16 + (long)((sel == 2) ? 3 : sel) * 589824;
            i = ((long)(wb - sel * 288) * 256 + tid) * 8;
        }
        float4 a = *(const float4*)(in + i);
        float4 c = *(const float4*)(in + i + 4);
        f16x8 o;
        o[0] = (f16)a.x; o[1] = (f16)a.y; o[2] = (f16)a.z; o[3] = (f16)a.w;
        o[4] = (f16)c.x; o[5] = (f16)c.y; o[6] = (f16)c.z; o[7] = (f16)c.w;
        *(f16x8*)&out[i] = o;
    } else if (b < 4080) {
        // wv tiled cvt + transpose: tile (tr,tc), 64x64
        const int tb = b - 3936;
        const int tr = tb / 12, tc = tb % 12;
        const int r  = tid >> 2;
        const int c0 = (tid & 3) * 16;
        const float* src = wv + ((long)tr * 64 + r) * 768 + tc * 64 + c0;
        float4 a0 = *(const float4*)(src);
        float4 a1 = *(const float4*)(src + 4);
        float4 a2 = *(const float4*)(src + 8);
        float4 a3 = *(const float4*)(src + 12);
        f16 vv[16];
        vv[0]=(f16)a0.x; vv[1]=(f16)a0.y; vv[2]=(f16)a0.z; vv[3]=(f16)a0.w;
        vv[4]=(f16)a1.x; vv[5]=(f16)a1.y; vv[6]=(f16)a1.z; vv[7]=(f16)a1.w;
        vv[8]=(f16)a2.x; vv[9]=(f16)a2.y; vv[10]=(f16)a2.z; vv[11]=(f16)a2.w;
        vv[12]=(f16)a3.x; vv[13]=(f16)a3.y; vv[14]=(f16)a3.z; vv[15]=(f16)a3.w;
        f16* wv16 = w16 + (long)2 * 589824;
        f16x8 o1, o2;
        #pragma unroll
        for (int i = 0; i < 8; ++i) { o1[i] = vv[i]; o2[i] = vv[8 + i]; }
        f16* d16 = wv16 + ((long)tr * 64 + r) * 768 + tc * 64 + c0;
        *(f16x8*)d16 = o1;
        *(f16x8*)(d16 + 8) = o2;
        #pragma unroll
        for (int i = 0; i < 16; ++i) t[r][c0 + i] = vv[i];
        __syncthreads();
        #pragma unroll
        for (int i = 0; i < 8; ++i) { o1[i] = t[c0 + i][r]; o2[i] = t[c0 + 8 + i][r]; }
        f16* dT = wvT + ((long)tc * 64 + r) * 768 + tr * 64 + c0;
        *(f16x8*)dT = o1;
        *(f16x8*)(dT + 8) = o2;
    } else {
        // c[d] = sum_h wo[d][h]*bv[h]; one wave per d, 16 iterations
        const int d0 = (b - 4080) * 64;
        const int wave = tid >> 6, lane = tid & 63;
        for (int it = 0; it < 16; ++it) {
            const int d = d0 + it * 4 + wave;
            float s = 0.f;
            #pragma unroll
            for (int j = 0; j < 12; ++j) {
                const int h = lane + 64 * j;
                s += wo[(long)d * 768 + h] * bv[h];
            }
            #pragma unroll
            for (int off = 32; off > 0; off >>= 1) s += __shfl_down(s, off);
            if (lane == 0) cB[d] = s;
        }
    }
}

// ---------------------------------------------------------------------------
// B=4, S=2048, D=H=768.  out = P @ (x@Wc^T + c) + bo, Wc = wo@wv, c = wo@bv
// (softmax rows sum to 1 -> bv passes through P as a constant).
// ws layout (bytes):
//   x16 @0 (12.6MB) | w16 @12582912 (4.7MB) | Q @17301504 | K @29884416
//   VWT @42467328 ([4][768][2048]) | S @55050240 (33.5MB)
//   wvT @88604672 | Wc @89784320 | c @90963968    total ~91 MB
// 5 dispatches: cvt+T+wobv | QK+Wc pool | S+VWT pool | softmax | PVout
// ---------------------------------------------------------------------------
extern "C" void kernel_launch(void* const* d_in, const int* in_sizes, int n_in,
                              void* d_out, int out_size, void* d_ws, size_t ws_size,
                              hipStream_t stream)
{
    const float* x  = (const float*)d_in[0];
    const float* wq = (const float*)d_in[1];
    const float* bq = (const float*)d_in[2];
    const float* wk = (const float*)d_in[3];
    const float* bk = (const float*)d_in[4];
    const float* wv = (const float*)d_in[5];
    const float* bv = (const float*)d_in[6];
    const float* wo = (const float*)d_in[7];
    const float* bo = (const float*)d_in[8];

    char* ws = (char*)d_ws;
    f16* x16  = (f16*)(ws + 0);
    f16* w16  = (f16*)(ws + 12582912);
    f16* Q    = (f16*)(ws + 17301504);
    f16* Kb   = (f16*)(ws + 29884416);
    f16* VWT  = (f16*)(ws + 42467328);
    f16* S    = (f16*)(ws + 55050240);
    f16* wvT  = (f16*)(ws + 88604672);
    f16* Wc   = (f16*)(ws + 89784320);
    float* cB = (float*)(ws + 90963968);

    f16* wo16 = w16 + 3 * 589824;

    // 1) all conversions + wv transpose + c = wo@bv
    cvt_all_kernel<<<4092, 256, 0, stream>>>(x, wq, wk, wv, wo, bv,
                                             x16, w16, wvT, cB);
    // 2) pool: QK-proj (768 blocks) + Wc = wo@wvT (36 blocks), flat 804
    gemm_kernel<f16, 128, 128, 4, 3><<<804, 256, 0, stream>>>(
        x16, 0, w16, 0, Q, 0, Kb, bq, bk, 1536, 768, wo16, wvT, Wc, nullptr);
    // 3) pool: S = Q@K^T (512 blocks, 128x256) + VWT = Wc@x^T + cB
    //    (192 blocks, 128x256), flat 704 = ~2.75 blocks/CU homogeneous
    gemm_kernel<f16, 128, 256, 5, 2><<<704, 256, 0, stream>>>(
        Q, 0, Kb, 0, S, 0, nullptr, nullptr, nullptr, 2048, 768,
        Wc, x16, VWT, cB);
    // 4) softmax
    softmax_kernel<<<8192, 256, 0, stream>>>(S);
    // 5) out[b][q][d] = sum_k P[q][k] VWT[d][k] + bo[d] : fp32 out, col-bias
    gemm_kernel<float, 128, 64, 1, 4><<<dim3(16, 12, 4), 256, 0, stream>>>(
        S, (long)2048 * 2048, VWT, (long)768 * 2048, d_out, (long)2048 * 768,
        nullptr, bo, nullptr, 768, 2048, nullptr, nullptr, nullptr, nullptr);
}